// Round 15
// baseline (1171.729 us; speedup 1.0000x reference)
//
#include <hip/hip_runtime.h>
#include <math.h>

#define BT 4096
#define CDIM 768
#define NHEAD 12
#define DH 64
#define TSEQ 1024
#define BBATCH 4

typedef _Float16 f16;
typedef __attribute__((ext_vector_type(4))) _Float16 f16x4;
typedef __attribute__((ext_vector_type(8))) _Float16 f16x8;
typedef __attribute__((ext_vector_type(4))) float f32x4;

// global_load_lds width=16: DMA HBM/L2 -> LDS, no VGPR round-trip.
// LDS dest is wave-uniform base + lane*16B (m104); per-lane GLOBAL address.
typedef const __attribute__((address_space(1))) unsigned int* gas1_t;
typedef __attribute__((address_space(3))) unsigned int* las3_t;
__device__ __forceinline__ void glds16(const void* g, void* l) {
  __builtin_amdgcn_global_load_lds((gas1_t)g, (las3_t)l, 16, 0, 0);
}

// ---------------- block reduction (256 threads = 4 waves) ----------------
__device__ __forceinline__ float block_reduce_sum(float v, float* sbuf) {
#pragma unroll
  for (int o = 32; o > 0; o >>= 1) v += __shfl_down(v, o, 64);
  int lane = threadIdx.x & 63;
  int w = threadIdx.x >> 6;
  if (lane == 0) sbuf[w] = v;
  __syncthreads();
  float r = sbuf[0] + sbuf[1] + sbuf[2] + sbuf[3];
  __syncthreads();
  return r;
}

// ---------------- zero-fill ----------------------------------------------
__global__ __launch_bounds__(256) void zero_kernel(float4* __restrict__ p) {
  p[(size_t)blockIdx.x * 256 + threadIdx.x] = make_float4(0.f, 0.f, 0.f, 0.f);
}

// ---------------- fp32 -> fp16 weight conversion (4 elems/thread) --------
__global__ __launch_bounds__(256) void cvt_f16_kernel(
    const float* __restrict__ in, f16* __restrict__ out) {
  size_t i = ((size_t)blockIdx.x * 256 + threadIdx.x) * 4;
  float4 v = *(const float4*)(in + i);
  f16x4 o = {(f16)v.x, (f16)v.y, (f16)v.z, (f16)v.w};
  *(f16x4*)(out + i) = o;
}

// ---------------- LN1: x_h = f16(LN(z + 0.1*emb + u) * w + b) ------------
// Used only for it=0 (z = 0). Later iterations get x_h from anderson_ln1.
__global__ __launch_bounds__(256) void ln1_kernel(
    const float* __restrict__ z, const float* __restrict__ u,
    const float* __restrict__ emb, const float* __restrict__ w,
    const float* __restrict__ b, f16* __restrict__ x) {
  __shared__ float sbuf[4];
  int row = blockIdx.x;
  int tid = threadIdx.x;
  const float* zr = z + (size_t)row * CDIM;
  const float* ur = u + (size_t)row * CDIM;
  float v[3];
  float s = 0.f;
#pragma unroll
  for (int i = 0; i < 3; i++) {
    int c = tid + i * 256;
    v[i] = zr[c] + 0.1f * emb[c] + ur[c];
    s += v[i];
  }
  s = block_reduce_sum(s, sbuf);
  float mu = s * (1.f / CDIM);
  float sq = 0.f;
#pragma unroll
  for (int i = 0; i < 3; i++) { v[i] -= mu; sq += v[i] * v[i]; }
  sq = block_reduce_sum(sq, sbuf);
  float rstd = rsqrtf(sq * (1.f / CDIM) + 1e-5f);
  f16* xr = x + (size_t)row * CDIM;
#pragma unroll
  for (int i = 0; i < 3; i++) {
    int c = tid + i * 256;
    xr[c] = (f16)(v[i] * rstd * w[c] + b[c]);
  }
}

// ---------------- LN2 + split-K residual pre-init -------------------------
// mlp2 runs split-K with atomicAdd into rcur: the epilogue terms
// (b2 + zattn - z) are hoisted here: rinit = zattn - z + b2.
__global__ __launch_bounds__(256) void ln2_kernel(
    const float* __restrict__ in, const float* __restrict__ w,
    const float* __restrict__ b, f16* __restrict__ x,
    const float* __restrict__ z, const float* __restrict__ b2,
    float* __restrict__ rinit) {
  __shared__ float sbuf[4];
  int row = blockIdx.x;
  int tid = threadIdx.x;
  const float* ir = in + (size_t)row * CDIM;
  const float* zr = z + (size_t)row * CDIM;
  float* rr = rinit + (size_t)row * CDIM;
  float v[3];
  float s = 0.f;
#pragma unroll
  for (int i = 0; i < 3; i++) {
    int c = tid + i * 256;
    v[i] = ir[c];
    rr[c] = v[i] - zr[c] + b2[c];
    s += v[i];
  }
  s = block_reduce_sum(s, sbuf);
  float mu = s * (1.f / CDIM);
  float sq = 0.f;
#pragma unroll
  for (int i = 0; i < 3; i++) { v[i] -= mu; sq += v[i] * v[i]; }
  sq = block_reduce_sum(sq, sbuf);
  float rstd = rsqrtf(sq * (1.f / CDIM) + 1e-5f);
  f16* xr = x + (size_t)row * CDIM;
#pragma unroll
  for (int i = 0; i < 3; i++) {
    int c = tid + i * 256;
    xr[c] = (f16)(v[i] * rstd * w[c] + b[c]);
  }
}

// erff GELU. R9's tanh-form gelu_fast perturbed register allocation in
// gemm_mfma<1> (scratch spill: WRITE_SIZE 25->61 MB, 43->57us). Do NOT
// swap this function without re-checking WRITE_SIZE on mlp1.
__device__ __forceinline__ float gelu_exact(float t) {
  return 0.5f * t * (1.f + erff(t * 0.70710678118654752f));
}

// ---------------- fp16 MFMA GEMM 128x128 v3: global_load_lds --------------
// R6-verified: m97 structure — linear LDS [128][64] f16, DMA staging via
// global_load_lds width=16, 2 barriers per K-step. XOR swizzle with
// PRE-SWIZZLED SOURCE (m173): R7 confirmed SQ_LDS_BANK_CONFLICT == 0.
// MODE 1: hout  = f16(gelu(acc + bias))            (mlp1)
// MODE 3: scatter f16 q/k to [B,H,T,64], v transposed to [B,H,64,T]
template <int MODE>
__global__ __launch_bounds__(256, 3) void gemm_mfma(
    const f16* __restrict__ A, const f16* __restrict__ W,
    const float* __restrict__ bias, f16* __restrict__ hq,
    f16* __restrict__ hk, f16* __restrict__ hvt, f16* __restrict__ hout,
    int M, int N, int K) {
  __shared__ __align__(16) f16 As[128 * 64];  // 16 KB, linear
  __shared__ __align__(16) f16 Bs[128 * 64];  // 16 KB, linear
  int tid = threadIdx.x;
  int wv = tid >> 6, lane = tid & 63;
  int bm = blockIdx.y, bn = blockIdx.x;
  int wm = (wv >> 1) * 64, wn = (wv & 1) * 64;

  // staging: wave wv covers rows wv*32 + j*8 + (lane>>3), j=0..3
  int srow = wv * 32 + (lane >> 3);
  int scole = 8 * ((lane & 7) ^ (lane >> 3));  // pre-swizzled source col
  const f16* gA = A + (size_t)(bm * 128 + srow) * K + scole;
  const f16* gB = W + (size_t)(bn * 128 + srow) * K + scole;

  f32x4 acc[4][4];
#pragma unroll
  for (int i = 0; i < 4; i++)
#pragma unroll
    for (int j = 0; j < 4; j++) acc[i][j] = (f32x4){0.f, 0.f, 0.f, 0.f};

  int am = lane & 15;
  int quad = lane >> 4;
  int sx = am & 7;  // read-side XOR key (== row&7 for all fragment rows)

  for (int k0 = 0; k0 < K; k0 += 64) {
    __syncthreads();  // previous tile fully consumed by all waves
#pragma unroll
    for (int j = 0; j < 4; j++) {
      glds16(gA + (size_t)(j * 8) * K + k0, &As[(wv * 32 + j * 8) * 64]);
      glds16(gB + (size_t)(j * 8) * K + k0, &Bs[(wv * 32 + j * 8) * 64]);
    }
    __syncthreads();  // vmcnt(0) drain: DMA landed, LDS ready
#pragma unroll
    for (int kk = 0; kk < 2; kk++) {
      int ce = 8 * (((kk << 2) + quad) ^ sx);  // swizzled col (elements)
      f16x8 af[4], bfr[4];
#pragma unroll
      for (int mi = 0; mi < 4; mi++)
        af[mi] = *(const f16x8*)&As[(wm + mi * 16 + am) * 64 + ce];
#pragma unroll
      for (int nj = 0; nj < 4; nj++)
        bfr[nj] = *(const f16x8*)&Bs[(wn + nj * 16 + am) * 64 + ce];
#pragma unroll
      for (int mi = 0; mi < 4; mi++)
#pragma unroll
        for (int nj = 0; nj < 4; nj++)
          acc[mi][nj] = __builtin_amdgcn_mfma_f32_16x16x32_f16(
              af[mi], bfr[nj], acc[mi][nj], 0, 0, 0);
    }
  }

  // C/D layout: col = lane&15, row = quad*4 + reg
  int crow0 = bm * 128 + wm + quad * 4;
  int ccol0 = bn * 128 + wn + am;
#pragma unroll
  for (int nj = 0; nj < 4; nj++) {
    int col = ccol0 + nj * 16;
    float bcol = bias[col];
    if constexpr (MODE == 3) {
      int which = col / CDIM;
      int rem = col - which * CDIM;
      int h = rem >> 6;
      int d = rem & 63;
#pragma unroll
      for (int mi = 0; mi < 4; mi++) {
#pragma unroll
        for (int r = 0; r < 4; r++) {
          int m = crow0 + mi * 16 + r;
          int bb = m >> 10, t = m & 1023;
          f16 val = (f16)(acc[mi][nj][r] + bcol);
          if (which == 0)
            hq[(((size_t)(bb * NHEAD + h) * TSEQ + t) << 6) + d] = val;
          else if (which == 1)
            hk[(((size_t)(bb * NHEAD + h) * TSEQ + t) << 6) + d] = val;
          else
            hvt[(((size_t)(bb * NHEAD + h) * DH + d) << 10) + t] = val;
        }
      }
    } else {  // MODE 1
#pragma unroll
      for (int mi = 0; mi < 4; mi++) {
#pragma unroll
        for (int r = 0; r < 4; r++) {
          int m = crow0 + mi * 16 + r;
          size_t idx = (size_t)m * N + col;
          hout[idx] = (f16)gelu_exact(acc[mi][nj][r] + bcol);
        }
      }
    }
  }
}

// ---------------- fp16 MFMA GEMM 64x64 glds (single buffer) ----------------
// R8/R11/R13-measured: mlp2 42.8-43.2us, VGPR 28, conflicts 0 — this
// template's floor. Tested exhaustively: occupancy (R4/R12/R13), barriers
// (R5), dbuf (R9/R10), tile 128^2 (R7), split-K 4 (R12) — all neutral or
// worse. No setprio here: m190 measured it null/negative on GEMM.
// MODE 0: fout0 = acc + bias + aux1               (out-proj residual)
// MODE 4: split-K=2 (blockIdx.z), no bias (in ln2's rinit), atomic epilogue
template <int MODE>
__global__ __launch_bounds__(256, 8) void gemm_glds64(
    const f16* __restrict__ A, const f16* __restrict__ W,
    const float* __restrict__ bias, const float* __restrict__ aux1,
    float* __restrict__ fout0, int M, int N, int K) {
  __shared__ __align__(16) f16 As[64 * 64];  // 8 KB, linear
  __shared__ __align__(16) f16 Bs[64 * 64];  // 8 KB, linear
  int tid = threadIdx.x;
  int wv = tid >> 6, lane = tid & 63;
  int bm = blockIdx.x, bn = blockIdx.y;  // transposed for XCD A-reuse
  int wm = (wv >> 1) * 32, wn = (wv & 1) * 32;

  int ks = (MODE == 4) ? blockIdx.z : 0;
  int kl = (MODE == 4) ? (K >> 1) : K;   // K-range length for this block

  // staging: wave wv covers rows wv*16 + j*8 + (lane>>3), j=0..1
  int srow = wv * 16 + (lane >> 3);
  int scole = 8 * ((lane & 7) ^ (lane >> 3));  // pre-swizzled source col
  const f16* gA = A + (size_t)(bm * 64 + srow) * K + ks * kl + scole;
  const f16* gB = W + (size_t)(bn * 64 + srow) * K + ks * kl + scole;

  f32x4 acc[2][2];
#pragma unroll
  for (int i = 0; i < 2; i++)
#pragma unroll
    for (int j = 0; j < 2; j++) acc[i][j] = (f32x4){0.f, 0.f, 0.f, 0.f};

  int am = lane & 15;
  int quad = lane >> 4;
  int sx = am & 7;

  for (int k0 = 0; k0 < kl; k0 += 64) {
    __syncthreads();
#pragma unroll
    for (int j = 0; j < 2; j++) {
      glds16(gA + (size_t)(j * 8) * K + k0, &As[(wv * 16 + j * 8) * 64]);
      glds16(gB + (size_t)(j * 8) * K + k0, &Bs[(wv * 16 + j * 8) * 64]);
    }
    __syncthreads();
#pragma unroll
    for (int kk = 0; kk < 2; kk++) {
      int ce = 8 * (((kk << 2) + quad) ^ sx);
      f16x8 af[2], bfr[2];
#pragma unroll
      for (int mi = 0; mi < 2; mi++)
        af[mi] = *(const f16x8*)&As[(wm + mi * 16 + am) * 64 + ce];
#pragma unroll
      for (int nj = 0; nj < 2; nj++)
        bfr[nj] = *(const f16x8*)&Bs[(wn + nj * 16 + am) * 64 + ce];
#pragma unroll
      for (int mi = 0; mi < 2; mi++)
#pragma unroll
        for (int nj = 0; nj < 2; nj++)
          acc[mi][nj] = __builtin_amdgcn_mfma_f32_16x16x32_f16(
              af[mi], bfr[nj], acc[mi][nj], 0, 0, 0);
    }
  }

  int crow0 = bm * 64 + wm + quad * 4;
  int ccol0 = bn * 64 + wn + am;
#pragma unroll
  for (int nj = 0; nj < 2; nj++) {
    int col = ccol0 + nj * 16;
#pragma unroll
    for (int mi = 0; mi < 2; mi++) {
#pragma unroll
      for (int r = 0; r < 4; r++) {
        int m = crow0 + mi * 16 + r;
        size_t idx = (size_t)m * N + col;
        if constexpr (MODE == 0) {
          fout0[idx] = acc[mi][nj][r] + bias[col] + aux1[idx];
        } else {  // MODE 4: raw partial sum into pre-initialized rcur
          unsafeAtomicAdd(fout0 + idx, acc[mi][nj][r]);
        }
      }
    }
  }
}

// ---------------- MFMA flash attention v9: glds K/V + setprio -------------
// R14-verified glds K/V staging (best total 1139us). R15 adds T5
// s_setprio(1) around the MFMA clusters: m191 measured +4-7% on attention
// where independent blocks co-reside at different phases (our regime: 3
// independent blocks/CU, each at its own KV-tile; no inter-block sync).
// GEMMs deliberately untouched (m190: null/negative on lockstep GEMM).
#define PSTRIDE 72
__global__ __launch_bounds__(256, 3) void flash_attn8(
    const f16* __restrict__ Qg, const f16* __restrict__ Kg,
    const f16* __restrict__ Vt, f16* __restrict__ attn) {
  __shared__ __align__(16) f16 Ks[64 * 64];  // 8 KB, linear swizzled
  __shared__ __align__(16) f16 Vs[64 * 64];  // 8 KB, linear swizzled
  __shared__ __align__(16) f16 Plds[4][16 * PSTRIDE];
  int tid = threadIdx.x;
  int wv = tid >> 6, lane = tid & 63;
  int bh = blockIdx.x;  // bh fastest: 16 blocks sharing K/V land on one XCD
  int bb = bh / NHEAD, h = bh % NHEAD;
  int m0 = (blockIdx.y * 4 + wv) * 16;
  int am = lane & 15;
  int quad = lane >> 4;
  int ak = quad * 8;
  int sx = am & 7;  // read-side XOR key

  // glds staging: wave wv covers rows wv*16 + j*8 + (lane>>3), j=0..1
  int srow = wv * 16 + (lane >> 3);
  int scole = 8 * ((lane & 7) ^ (lane >> 3));  // pre-swizzled source col

  const f16* kb = Kg + (((size_t)bh * TSEQ) << 6);
  const f16* vb = Vt + (((size_t)bh * DH) << 10);
  const f16* kg = kb + (size_t)srow * 64 + scole;      // K: [T][64]
  const f16* vg = vb + (size_t)srow * TSEQ + scole;    // V^T: [64][T]

  const f16* qbase = Qg + (((size_t)bh * TSEQ + m0) << 6);
  f16x8 qf0 = *(const f16x8*)(qbase + am * 64 + ak);
  f16x8 qf1 = *(const f16x8*)(qbase + am * 64 + 32 + ak);
#pragma unroll
  for (int i = 0; i < 8; i++) { qf0[i] *= (f16)0.125f; qf1[i] *= (f16)0.125f; }

  f16* Pw = Plds[wv];
  f32x4 Oa[4];
#pragma unroll
  for (int i = 0; i < 4; i++) Oa[i] = (f32x4){0.f, 0.f, 0.f, 0.f};
  float lpart[4] = {0.f, 0.f, 0.f, 0.f};

  for (int n0 = 0; n0 < TSEQ; n0 += 64) {
    __syncthreads();  // previous tile fully consumed
#pragma unroll
    for (int j = 0; j < 2; j++) {
      glds16(kg + (size_t)(n0 + j * 8) * 64, &Ks[(wv * 16 + j * 8) * 64]);
      glds16(vg + (size_t)(j * 8) * TSEQ + n0, &Vs[(wv * 16 + j * 8) * 64]);
    }
    __syncthreads();  // vmcnt(0) drain: K/V tile landed

    int ce0 = 8 * (quad ^ sx);        // logical slot quad
    int ce1 = 8 * ((quad + 4) ^ sx);  // logical slot quad+4
    f32x4 S[4];
    __builtin_amdgcn_s_setprio(1);
#pragma unroll
    for (int t = 0; t < 4; t++) {
      f16x8 kf0 = *(const f16x8*)&Ks[(16 * t + am) * 64 + ce0];
      f16x8 kf1 = *(const f16x8*)&Ks[(16 * t + am) * 64 + ce1];
      S[t] = __builtin_amdgcn_mfma_f32_16x16x32_f16(
          qf0, kf0, (f32x4){0.f, 0.f, 0.f, 0.f}, 0, 0, 0);
      S[t] = __builtin_amdgcn_mfma_f32_16x16x32_f16(qf1, kf1, S[t], 0, 0, 0);
    }
    __builtin_amdgcn_s_setprio(0);
#pragma unroll
    for (int t = 0; t < 4; t++) {
#pragma unroll
      for (int r = 0; r < 4; r++) {
        float p = __expf(S[t][r]);
        lpart[r] += p;
        Pw[(quad * 4 + r) * PSTRIDE + 16 * t + am] = (f16)p;
      }
    }
    f16x8 pa0 = *(const f16x8*)&Pw[am * PSTRIDE + ak];
    f16x8 pa1 = *(const f16x8*)&Pw[am * PSTRIDE + 32 + ak];
    __builtin_amdgcn_s_setprio(1);
#pragma unroll
    for (int dt = 0; dt < 4; dt++) {
      f16x8 vf0 = *(const f16x8*)&Vs[(16 * dt + am) * 64 + ce0];
      f16x8 vf1 = *(const f16x8*)&Vs[(16 * dt + am) * 64 + ce1];
      Oa[dt] = __builtin_amdgcn_mfma_f32_16x16x32_f16(pa0, vf0, Oa[dt], 0, 0, 0);
      Oa[dt] = __builtin_amdgcn_mfma_f32_16x16x32_f16(pa1, vf1, Oa[dt], 0, 0, 0);
    }
    __builtin_amdgcn_s_setprio(0);
  }

#pragma unroll
  for (int o = 1; o < 16; o <<= 1)
#pragma unroll
    for (int r = 0; r < 4; r++) lpart[r] += __shfl_xor(lpart[r], o, 64);

#pragma unroll
  for (int r = 0; r < 4; r++) {
    int m = m0 + quad * 4 + r;
    float inv = 1.f / lpart[r];
    f16* orow = attn + ((size_t)(bb * TSEQ + m)) * CDIM + h * DH;
#pragma unroll
    for (int dt = 0; dt < 4; dt++)
      orow[dt * 16 + am] = (f16)(Oa[dt][r] * inv);
  }
}

// ---------------- Anderson update fused with next iteration's LN1 --------
template <int KA>
__global__ __launch_bounds__(256) void anderson_ln1(
    float* __restrict__ z, const float* __restrict__ rescur,
    const float* __restrict__ p0, const float* __restrict__ p1,
    const float* __restrict__ p2, const float* __restrict__ p3,
    const float* __restrict__ u, const float* __restrict__ emb,
    const float* __restrict__ w, const float* __restrict__ b,
    f16* __restrict__ x) {
  __shared__ float sbuf[4];
  int row = blockIdx.x, tid = threadIdx.x;
  size_t base = (size_t)row * CDIM + tid;
  float r[3];
#pragma unroll
  for (int i = 0; i < 3; i++) r[i] = rescur[base + i * 256];

  float zn[3];
  if constexpr (KA == 0) {
#pragma unroll
    for (int i = 0; i < 3; i++) zn[i] = z[base + i * 256] + r[i];
  } else {
    const float* ps[4] = {p0, p1, p2, p3};
    float dF[KA == 0 ? 1 : KA][3];
#pragma unroll
    for (int k = 0; k < KA; k++)
#pragma unroll
      for (int i = 0; i < 3; i++) dF[k][i] = ps[k][base + i * 256] - r[i];

    float Gm[KA == 0 ? 1 : KA][KA == 0 ? 1 : KA], bv[KA == 0 ? 1 : KA];
#pragma unroll
    for (int k = 0; k < KA; k++) {
#pragma unroll
      for (int ll = k; ll < KA; ll++) {
        float p = 0.f;
#pragma unroll
        for (int i = 0; i < 3; i++) p += dF[k][i] * dF[ll][i];
        float t = block_reduce_sum(p, sbuf);
        Gm[k][ll] = t;
        Gm[ll][k] = t;
      }
    }
#pragma unroll
    for (int k = 0; k < KA; k++) Gm[k][k] += 1e-6f;
#pragma unroll
    for (int k = 0; k < KA; k++) {
      float p = 0.f;
#pragma unroll
      for (int i = 0; i < 3; i++) p += dF[k][i] * r[i];
      bv[k] = block_reduce_sum(p, sbuf);
    }
    float alpha[KA == 0 ? 1 : KA];
#pragma unroll
    for (int p = 0; p < KA; p++) {
      float inv = 1.f / Gm[p][p];
#pragma unroll
      for (int rr = p + 1; rr < KA; rr++) {
        float f = Gm[rr][p] * inv;
#pragma unroll
        for (int c = p; c < KA; c++) Gm[rr][c] -= f * Gm[p][c];
        bv[rr] -= f * bv[p];
      }
    }
#pragma unroll
    for (int p = KA - 1; p >= 0; p--) {
      float s2 = bv[p];
#pragma unroll
      for (int c = p + 1; c < KA; c++) s2 -= Gm[p][c] * alpha[c];
      alpha[p] = s2 / Gm[p][p];
    }
#pragma unroll
    for (int i = 0; i < 3; i++) {
      float d = r[i];
#pragma unroll
      for (int k = 0; k < KA; k++) d = fmaf(-dF[k][i], alpha[k], d);
      zn[i] = z[base + i * 256] + d;
    }
  }
#pragma unroll
  for (int i = 0; i < 3; i++) z[base + i * 256] = zn[i];

  // ---- fused LN1 for next iteration ----
  const float* ur = u + (size_t)row * CDIM;
  float v[3];
  float s = 0.f;
#pragma unroll
  for (int i = 0; i < 3; i++) {
    int c = tid + i * 256;
    v[i] = zn[i] + 0.1f * emb[c] + ur[c];
    s += v[i];
  }
  s = block_reduce_sum(s, sbuf);
  float mu = s * (1.f / CDIM);
  float sq = 0.f;
#pragma unroll
  for (int i = 0; i < 3; i++) { v[i] -= mu; sq += v[i] * v[i]; }
  sq = block_reduce_sum(sq, sbuf);
  float rstd = rsqrtf(sq * (1.f / CDIM) + 1e-5f);
  f16* xr = x + (size_t)row * CDIM;
#pragma unroll
  for (int i = 0; i < 3; i++) {
    int c = tid + i * 256;
    xr[c] = (f16)(v[i] * rstd * w[c] + b[c]);
  }
}

// ---------------- Anderson (final iteration, no LN) -----------------------
template <int KA>
__global__ __launch_bounds__(256) void anderson_kernel(
    float* __restrict__ z, const float* __restrict__ rescur,
    const float* __restrict__ p0, const float* __restrict__ p1,
    const float* __restrict__ p2, const float* __restrict__ p3) {
  __shared__ float sbuf[4];
  int row = blockIdx.x, tid = threadIdx.x;
  size_t base = (size_t)row * CDIM + tid;
  float r[3];
#pragma unroll
  for (int i = 0; i < 3; i++) r[i] = rescur[base + i * 256];
  const float* ps[4] = {p0, p1, p2, p3};
  float dF[KA][3];
#pragma unroll
  for (int k = 0; k < KA; k++)
#pragma unroll
    for (int i = 0; i < 3; i++) dF[k][i] = ps[k][base + i * 256] - r[i];

  float Gm[KA][KA], bv[KA];
#pragma unroll
  for (int k = 0; k < KA; k++) {
#pragma unroll
    for (int ll = k; ll < KA; ll++) {
      float p = 0.f;
#pragma unroll
      for (int i = 0; i < 3; i++) p += dF[k][i] * dF[ll][i];
      float t = block_reduce_sum(p, sbuf);
      Gm[k][ll] = t;
      Gm[ll][k] = t;
    }
  }
#pragma unroll
  for (int k = 0; k < KA; k++) Gm[k][k] += 1e-6f;
#pragma unroll
  for (int k = 0; k < KA; k++) {
    float p = 0.f;
#pragma unroll
    for (int i = 0; i < 3; i++) p += dF[k][i] * r[i];
    bv[k] = block_reduce_sum(p, sbuf);
  }
  float alpha[KA];
#pragma unroll
  for (int p = 0; p < KA; p++) {
    float inv = 1.f / Gm[p][p];
#pragma unroll
    for (int rr = p + 1; rr < KA; rr++) {
      float f = Gm[rr][p] * inv;
#pragma unroll
      for (int c = p; c < KA; c++) Gm[rr][c] -= f * Gm[p][c];
      bv[rr] -= f * bv[p];
    }
  }
#pragma unroll
  for (int p = KA - 1; p >= 0; p--) {
    float s2 = bv[p];
#pragma unroll
    for (int c = p + 1; c < KA; c++) s2 -= Gm[p][c] * alpha[c];
    alpha[p] = s2 / Gm[p][p];
  }
#pragma unroll
  for (int i = 0; i < 3; i++) {
    float d = r[i];
#pragma unroll
    for (int k = 0; k < KA; k++) d = fmaf(-dF[k][i], alpha[k], d);
    z[base + i * 256] += d;
  }
}

extern "C" void kernel_launch(void* const* d_in, const int* in_sizes, int n_in,
                              void* d_out, int out_size, void* d_ws,
                              size_t ws_size, hipStream_t stream) {
  (void)in_sizes; (void)n_in; (void)out_size; (void)ws_size;
  const float* u = (const float*)d_in[0];
  const float* iter_emb = (const float*)d_in[1];
  const float* ln1w = (const float*)d_in[2];
  const float* ln1b = (const float*)d_in[3];
  const float* wqkv = (const float*)d_in[4];
  const float* bqkv = (const float*)d_in[5];
  const float* wo = (const float*)d_in[6];
  const float* bo = (const float*)d_in[7];
  const float* ln2w = (const float*)d_in[8];
  const float* ln2b = (const float*)d_in[9];
  const float* w1 = (const float*)d_in[10];
  const float* b1 = (const float*)d_in[11];
  const float* w2 = (const float*)d_in[12];
  const float* b2 = (const float*)d_in[13];

  const size_t S = (size_t)BT * CDIM;  // 3,145,728
  float* ws = (float*)d_ws;
  // fp32 slots:
  float* z = ws + 0 * S;
  float* zattn = ws + 1 * S;
  float* res[5] = {ws + 2 * S, ws + 3 * S, ws + 4 * S, ws + 5 * S, ws + 6 * S};
  // f16 region:
  f16* q_h = (f16*)(ws + 7 * S);   // S f16: [7.0,7.5)   [B,H,T,64]
  f16* k_h = q_h + S;              // [7.5,8.0)          [B,H,T,64]
  f16* vt_h = q_h + 2 * S;         // [8.0,8.5)          [B,H,64,T]
  f16* h_h = (f16*)(ws + 7 * S);   // 4S f16 [7.0,9.0) — aliases q/k/vt
                                   // (disjoint lifetime: mlp1..mlp2 only)
  f16* x_h = (f16*)(ws + 9 * S);   // S f16 [9.0,9.5): LN out / attn out
  f16* wqkv_h = x_h + S;
  f16* wo_h = wqkv_h + (size_t)3 * CDIM * CDIM;
  f16* w1_h = wo_h + (size_t)CDIM * CDIM;
  f16* w2_h = w1_h + (size_t)4 * CDIM * CDIM;

  cvt_f16_kernel<<<1728, 256, 0, stream>>>(wqkv, wqkv_h);
  cvt_f16_kernel<<<576, 256, 0, stream>>>(wo, wo_h);
  cvt_f16_kernel<<<2304, 256, 0, stream>>>(w1, w1_h);
  cvt_f16_kernel<<<2304, 256, 0, stream>>>(w2, w2_h);
  zero_kernel<<<S / 1024, 256, 0, stream>>>((float4*)z);

  for (int it = 0; it < 6; it++) {
    float* rcur = res[it % 5];
    if (it == 0) {
      ln1_kernel<<<BT, 256, 0, stream>>>(z, u, iter_emb, ln1w, ln1b, x_h);
    }
    // (it>0: x_h was produced by the fused anderson_ln1 of iteration it-1)
    gemm_mfma<3><<<dim3(18, 32), 256, 0, stream>>>(
        x_h, wqkv_h, bqkv, q_h, k_h, vt_h, nullptr, BT, 3 * CDIM, CDIM);
    flash_attn8<<<dim3(BBATCH * NHEAD, TSEQ / 64), 256, 0, stream>>>(
        q_h, k_h, vt_h, x_h);
    gemm_glds64<0><<<dim3(64, 12), 256, 0, stream>>>(
        x_h, wo_h, bo, z, zattn, BT, CDIM, CDIM);
    // ln2 also pre-initializes rcur = zattn - z + b2 for split-K atomics
    ln2_kernel<<<BT, 256, 0, stream>>>(zattn, ln2w, ln2b, x_h, z, b2, rcur);
    gemm_mfma<1><<<dim3(24, 32), 256, 0, stream>>>(
        x_h, w1_h, b1, nullptr, nullptr, nullptr, h_h, BT, 4 * CDIM, CDIM);
    gemm_glds64<4><<<dim3(64, 12, 2), 256, 0, stream>>>(
        h_h, w2_h, b2, nullptr, rcur, BT, CDIM, 4 * CDIM);

    int Kh = it < 4 ? it : 4;
    const float* p[4] = {rcur, rcur, rcur, rcur};
    for (int kx = 1; kx <= Kh; kx++) p[kx - 1] = res[(it - kx) % 5];
    if (it < 5) {
      const float* embn = iter_emb + (it + 1) * CDIM;
      switch (Kh) {
        case 0: anderson_ln1<0><<<BT, 256, 0, stream>>>(z, rcur, p[0], p[1], p[2], p[3], u, embn, ln1w, ln1b, x_h); break;
        case 1: anderson_ln1<1><<<BT, 256, 0, stream>>>(z, rcur, p[0], p[1], p[2], p[3], u, embn, ln1w, ln1b, x_h); break;
        case 2: anderson_ln1<2><<<BT, 256, 0, stream>>>(z, rcur, p[0], p[1], p[2], p[3], u, embn, ln1w, ln1b, x_h); break;
        case 3: anderson_ln1<3><<<BT, 256, 0, stream>>>(z, rcur, p[0], p[1], p[2], p[3], u, embn, ln1w, ln1b, x_h); break;
        default: anderson_ln1<4><<<BT, 256, 0, stream>>>(z, rcur, p[0], p[1], p[2], p[3], u, embn, ln1w, ln1b, x_h); break;
      }
    } else {
      anderson_kernel<4><<<BT, 256, 0, stream>>>(z, rcur, p[0], p[1], p[2], p[3]);
    }
  }
  hipMemcpyAsync(d_out, z, S * sizeof(float), hipMemcpyDeviceToDevice, stream);
}

// Round 16
// 1126.251 us; speedup vs baseline: 1.0404x; 1.0404x over previous
//
#include <hip/hip_runtime.h>
#include <math.h>

#define BT 4096
#define CDIM 768
#define NHEAD 12
#define DH 64
#define TSEQ 1024
#define BBATCH 4

typedef _Float16 f16;
typedef __attribute__((ext_vector_type(4))) _Float16 f16x4;
typedef __attribute__((ext_vector_type(8))) _Float16 f16x8;
typedef __attribute__((ext_vector_type(4))) float f32x4;

// global_load_lds width=16: DMA HBM/L2 -> LDS, no VGPR round-trip.
// LDS dest is wave-uniform base + lane*16B (m104); per-lane GLOBAL address.
typedef const __attribute__((address_space(1))) unsigned int* gas1_t;
typedef __attribute__((address_space(3))) unsigned int* las3_t;
__device__ __forceinline__ void glds16(const void* g, void* l) {
  __builtin_amdgcn_global_load_lds((gas1_t)g, (las3_t)l, 16, 0, 0);
}

// ---------------- block reduction (256 threads = 4 waves) ----------------
__device__ __forceinline__ float block_reduce_sum(float v, float* sbuf) {
#pragma unroll
  for (int o = 32; o > 0; o >>= 1) v += __shfl_down(v, o, 64);
  int lane = threadIdx.x & 63;
  int w = threadIdx.x >> 6;
  if (lane == 0) sbuf[w] = v;
  __syncthreads();
  float r = sbuf[0] + sbuf[1] + sbuf[2] + sbuf[3];
  __syncthreads();
  return r;
}

// ---------------- zero-fill ----------------------------------------------
__global__ __launch_bounds__(256) void zero_kernel(float4* __restrict__ p) {
  p[(size_t)blockIdx.x * 256 + threadIdx.x] = make_float4(0.f, 0.f, 0.f, 0.f);
}

// ---------------- fp32 -> fp16 weight conversion (4 elems/thread) --------
__global__ __launch_bounds__(256) void cvt_f16_kernel(
    const float* __restrict__ in, f16* __restrict__ out) {
  size_t i = ((size_t)blockIdx.x * 256 + threadIdx.x) * 4;
  float4 v = *(const float4*)(in + i);
  f16x4 o = {(f16)v.x, (f16)v.y, (f16)v.z, (f16)v.w};
  *(f16x4*)(out + i) = o;
}

// ---------------- LN1: x_h = f16(LN(z + 0.1*emb + u) * w + b) ------------
// Used only for it=0 (z = 0). Later iterations get x_h from anderson_ln1.
__global__ __launch_bounds__(256) void ln1_kernel(
    const float* __restrict__ z, const float* __restrict__ u,
    const float* __restrict__ emb, const float* __restrict__ w,
    const float* __restrict__ b, f16* __restrict__ x) {
  __shared__ float sbuf[4];
  int row = blockIdx.x;
  int tid = threadIdx.x;
  const float* zr = z + (size_t)row * CDIM;
  const float* ur = u + (size_t)row * CDIM;
  float v[3];
  float s = 0.f;
#pragma unroll
  for (int i = 0; i < 3; i++) {
    int c = tid + i * 256;
    v[i] = zr[c] + 0.1f * emb[c] + ur[c];
    s += v[i];
  }
  s = block_reduce_sum(s, sbuf);
  float mu = s * (1.f / CDIM);
  float sq = 0.f;
#pragma unroll
  for (int i = 0; i < 3; i++) { v[i] -= mu; sq += v[i] * v[i]; }
  sq = block_reduce_sum(sq, sbuf);
  float rstd = rsqrtf(sq * (1.f / CDIM) + 1e-5f);
  f16* xr = x + (size_t)row * CDIM;
#pragma unroll
  for (int i = 0; i < 3; i++) {
    int c = tid + i * 256;
    xr[c] = (f16)(v[i] * rstd * w[c] + b[c]);
  }
}

// ---------------- LN2 + split-K residual pre-init -------------------------
// mlp2 runs split-K with atomicAdd into rcur: the epilogue terms
// (b2 + zattn - z) are hoisted here: rinit = zattn - z + b2.
__global__ __launch_bounds__(256) void ln2_kernel(
    const float* __restrict__ in, const float* __restrict__ w,
    const float* __restrict__ b, f16* __restrict__ x,
    const float* __restrict__ z, const float* __restrict__ b2,
    float* __restrict__ rinit) {
  __shared__ float sbuf[4];
  int row = blockIdx.x;
  int tid = threadIdx.x;
  const float* ir = in + (size_t)row * CDIM;
  const float* zr = z + (size_t)row * CDIM;
  float* rr = rinit + (size_t)row * CDIM;
  float v[3];
  float s = 0.f;
#pragma unroll
  for (int i = 0; i < 3; i++) {
    int c = tid + i * 256;
    v[i] = ir[c];
    rr[c] = v[i] - zr[c] + b2[c];
    s += v[i];
  }
  s = block_reduce_sum(s, sbuf);
  float mu = s * (1.f / CDIM);
  float sq = 0.f;
#pragma unroll
  for (int i = 0; i < 3; i++) { v[i] -= mu; sq += v[i] * v[i]; }
  sq = block_reduce_sum(sq, sbuf);
  float rstd = rsqrtf(sq * (1.f / CDIM) + 1e-5f);
  f16* xr = x + (size_t)row * CDIM;
#pragma unroll
  for (int i = 0; i < 3; i++) {
    int c = tid + i * 256;
    xr[c] = (f16)(v[i] * rstd * w[c] + b[c]);
  }
}

// erff GELU. R9's tanh-form gelu_fast perturbed register allocation in
// gemm_mfma<1> (scratch spill: WRITE_SIZE 25->61 MB, 43->57us). Do NOT
// swap this function without re-checking WRITE_SIZE on mlp1.
__device__ __forceinline__ float gelu_exact(float t) {
  return 0.5f * t * (1.f + erff(t * 0.70710678118654752f));
}

// ---------------- fp16 MFMA GEMM 128x128 v3: global_load_lds --------------
// R6-verified: m97 structure — linear LDS [128][64] f16, DMA staging via
// global_load_lds width=16, 2 barriers per K-step. XOR swizzle with
// PRE-SWIZZLED SOURCE (m173): R7 confirmed SQ_LDS_BANK_CONFLICT == 0.
// MODE 1: hout  = f16(gelu(acc + bias))            (mlp1)
// MODE 3: scatter f16 q/k to [B,H,T,64], v transposed to [B,H,64,T]
template <int MODE>
__global__ __launch_bounds__(256, 3) void gemm_mfma(
    const f16* __restrict__ A, const f16* __restrict__ W,
    const float* __restrict__ bias, f16* __restrict__ hq,
    f16* __restrict__ hk, f16* __restrict__ hvt, f16* __restrict__ hout,
    int M, int N, int K) {
  __shared__ __align__(16) f16 As[128 * 64];  // 16 KB, linear
  __shared__ __align__(16) f16 Bs[128 * 64];  // 16 KB, linear
  int tid = threadIdx.x;
  int wv = tid >> 6, lane = tid & 63;
  int bm = blockIdx.y, bn = blockIdx.x;
  int wm = (wv >> 1) * 64, wn = (wv & 1) * 64;

  // staging: wave wv covers rows wv*32 + j*8 + (lane>>3), j=0..3
  int srow = wv * 32 + (lane >> 3);
  int scole = 8 * ((lane & 7) ^ (lane >> 3));  // pre-swizzled source col
  const f16* gA = A + (size_t)(bm * 128 + srow) * K + scole;
  const f16* gB = W + (size_t)(bn * 128 + srow) * K + scole;

  f32x4 acc[4][4];
#pragma unroll
  for (int i = 0; i < 4; i++)
#pragma unroll
    for (int j = 0; j < 4; j++) acc[i][j] = (f32x4){0.f, 0.f, 0.f, 0.f};

  int am = lane & 15;
  int quad = lane >> 4;
  int sx = am & 7;  // read-side XOR key (== row&7 for all fragment rows)

  for (int k0 = 0; k0 < K; k0 += 64) {
    __syncthreads();  // previous tile fully consumed by all waves
#pragma unroll
    for (int j = 0; j < 4; j++) {
      glds16(gA + (size_t)(j * 8) * K + k0, &As[(wv * 32 + j * 8) * 64]);
      glds16(gB + (size_t)(j * 8) * K + k0, &Bs[(wv * 32 + j * 8) * 64]);
    }
    __syncthreads();  // vmcnt(0) drain: DMA landed, LDS ready
#pragma unroll
    for (int kk = 0; kk < 2; kk++) {
      int ce = 8 * (((kk << 2) + quad) ^ sx);  // swizzled col (elements)
      f16x8 af[4], bfr[4];
#pragma unroll
      for (int mi = 0; mi < 4; mi++)
        af[mi] = *(const f16x8*)&As[(wm + mi * 16 + am) * 64 + ce];
#pragma unroll
      for (int nj = 0; nj < 4; nj++)
        bfr[nj] = *(const f16x8*)&Bs[(wn + nj * 16 + am) * 64 + ce];
#pragma unroll
      for (int mi = 0; mi < 4; mi++)
#pragma unroll
        for (int nj = 0; nj < 4; nj++)
          acc[mi][nj] = __builtin_amdgcn_mfma_f32_16x16x32_f16(
              af[mi], bfr[nj], acc[mi][nj], 0, 0, 0);
    }
  }

  // C/D layout: col = lane&15, row = quad*4 + reg
  int crow0 = bm * 128 + wm + quad * 4;
  int ccol0 = bn * 128 + wn + am;
#pragma unroll
  for (int nj = 0; nj < 4; nj++) {
    int col = ccol0 + nj * 16;
    float bcol = bias[col];
    if constexpr (MODE == 3) {
      int which = col / CDIM;
      int rem = col - which * CDIM;
      int h = rem >> 6;
      int d = rem & 63;
#pragma unroll
      for (int mi = 0; mi < 4; mi++) {
#pragma unroll
        for (int r = 0; r < 4; r++) {
          int m = crow0 + mi * 16 + r;
          int bb = m >> 10, t = m & 1023;
          f16 val = (f16)(acc[mi][nj][r] + bcol);
          if (which == 0)
            hq[(((size_t)(bb * NHEAD + h) * TSEQ + t) << 6) + d] = val;
          else if (which == 1)
            hk[(((size_t)(bb * NHEAD + h) * TSEQ + t) << 6) + d] = val;
          else
            hvt[(((size_t)(bb * NHEAD + h) * DH + d) << 10) + t] = val;
        }
      }
    } else {  // MODE 1
#pragma unroll
      for (int mi = 0; mi < 4; mi++) {
#pragma unroll
        for (int r = 0; r < 4; r++) {
          int m = crow0 + mi * 16 + r;
          size_t idx = (size_t)m * N + col;
          hout[idx] = (f16)gelu_exact(acc[mi][nj][r] + bcol);
        }
      }
    }
  }
}

// ---------------- fp16 MFMA GEMM 64x64 glds (single buffer) ----------------
// R8/R11/R13-measured: mlp2 42.8-43.2us, VGPR 28, conflicts 0 — this
// template's floor. Tested exhaustively: occupancy (R4/R12/R13), barriers
// (R5), dbuf (R9/R10), tile 128^2 (R7), split-K 4 (R12) — all neutral or
// worse. No setprio: m190 + R15 both measured it null/negative here.
// MODE 0: fout0 = acc + bias + aux1               (out-proj residual)
// MODE 4: split-K=2 (blockIdx.z), no bias (in ln2's rinit), atomic epilogue
template <int MODE>
__global__ __launch_bounds__(256, 8) void gemm_glds64(
    const f16* __restrict__ A, const f16* __restrict__ W,
    const float* __restrict__ bias, const float* __restrict__ aux1,
    float* __restrict__ fout0, int M, int N, int K) {
  __shared__ __align__(16) f16 As[64 * 64];  // 8 KB, linear
  __shared__ __align__(16) f16 Bs[64 * 64];  // 8 KB, linear
  int tid = threadIdx.x;
  int wv = tid >> 6, lane = tid & 63;
  int bm = blockIdx.x, bn = blockIdx.y;  // transposed for XCD A-reuse
  int wm = (wv >> 1) * 32, wn = (wv & 1) * 32;

  int ks = (MODE == 4) ? blockIdx.z : 0;
  int kl = (MODE == 4) ? (K >> 1) : K;   // K-range length for this block

  // staging: wave wv covers rows wv*16 + j*8 + (lane>>3), j=0..1
  int srow = wv * 16 + (lane >> 3);
  int scole = 8 * ((lane & 7) ^ (lane >> 3));  // pre-swizzled source col
  const f16* gA = A + (size_t)(bm * 64 + srow) * K + ks * kl + scole;
  const f16* gB = W + (size_t)(bn * 64 + srow) * K + ks * kl + scole;

  f32x4 acc[2][2];
#pragma unroll
  for (int i = 0; i < 2; i++)
#pragma unroll
    for (int j = 0; j < 2; j++) acc[i][j] = (f32x4){0.f, 0.f, 0.f, 0.f};

  int am = lane & 15;
  int quad = lane >> 4;
  int sx = am & 7;

  for (int k0 = 0; k0 < kl; k0 += 64) {
    __syncthreads();
#pragma unroll
    for (int j = 0; j < 2; j++) {
      glds16(gA + (size_t)(j * 8) * K + k0, &As[(wv * 16 + j * 8) * 64]);
      glds16(gB + (size_t)(j * 8) * K + k0, &Bs[(wv * 16 + j * 8) * 64]);
    }
    __syncthreads();
#pragma unroll
    for (int kk = 0; kk < 2; kk++) {
      int ce = 8 * (((kk << 2) + quad) ^ sx);
      f16x8 af[2], bfr[2];
#pragma unroll
      for (int mi = 0; mi < 2; mi++)
        af[mi] = *(const f16x8*)&As[(wm + mi * 16 + am) * 64 + ce];
#pragma unroll
      for (int nj = 0; nj < 2; nj++)
        bfr[nj] = *(const f16x8*)&Bs[(wn + nj * 16 + am) * 64 + ce];
#pragma unroll
      for (int mi = 0; mi < 2; mi++)
#pragma unroll
        for (int nj = 0; nj < 2; nj++)
          acc[mi][nj] = __builtin_amdgcn_mfma_f32_16x16x32_f16(
              af[mi], bfr[nj], acc[mi][nj], 0, 0, 0);
    }
  }

  int crow0 = bm * 64 + wm + quad * 4;
  int ccol0 = bn * 64 + wn + am;
#pragma unroll
  for (int nj = 0; nj < 2; nj++) {
    int col = ccol0 + nj * 16;
#pragma unroll
    for (int mi = 0; mi < 2; mi++) {
#pragma unroll
      for (int r = 0; r < 4; r++) {
        int m = crow0 + mi * 16 + r;
        size_t idx = (size_t)m * N + col;
        if constexpr (MODE == 0) {
          fout0[idx] = acc[mi][nj][r] + bias[col] + aux1[idx];
        } else {  // MODE 4: raw partial sum into pre-initialized rcur
          unsafeAtomicAdd(fout0 + idx, acc[mi][nj][r]);
        }
      }
    }
  }
}

// ---------------- MFMA flash attention v9: glds K/V staging ---------------
// R14-verified (best total 1139us): K/V staging via the proven glds+XOR-
// swizzle path. K is [T,64] row-major, V^T is [64,T]: both stage
// 8-rows-per-glds16 with row = lane>>3, pre-swizzled source col
// 8*((lane&7)^(lane>>3)). Fragment reads: row&7 == am&7; logical col slot
// q in {quad, quad+4} lives at physical slot q^(am&7).
// R15's setprio on the MFMA clusters REGRESSED (~1172 vs 1139): our
// attention blocks are 4-wave barrier-synced (not independent 1-wave
// blocks like m191's win case) — the boosted wave just stalls at the
// barrier while starving the sibling block's staging. Reverted.
#define PSTRIDE 72
__global__ __launch_bounds__(256, 3) void flash_attn8(
    const f16* __restrict__ Qg, const f16* __restrict__ Kg,
    const f16* __restrict__ Vt, f16* __restrict__ attn) {
  __shared__ __align__(16) f16 Ks[64 * 64];  // 8 KB, linear swizzled
  __shared__ __align__(16) f16 Vs[64 * 64];  // 8 KB, linear swizzled
  __shared__ __align__(16) f16 Plds[4][16 * PSTRIDE];
  int tid = threadIdx.x;
  int wv = tid >> 6, lane = tid & 63;
  int bh = blockIdx.x;  // bh fastest: 16 blocks sharing K/V land on one XCD
  int bb = bh / NHEAD, h = bh % NHEAD;
  int m0 = (blockIdx.y * 4 + wv) * 16;
  int am = lane & 15;
  int quad = lane >> 4;
  int ak = quad * 8;
  int sx = am & 7;  // read-side XOR key

  // glds staging: wave wv covers rows wv*16 + j*8 + (lane>>3), j=0..1
  int srow = wv * 16 + (lane >> 3);
  int scole = 8 * ((lane & 7) ^ (lane >> 3));  // pre-swizzled source col

  const f16* kb = Kg + (((size_t)bh * TSEQ) << 6);
  const f16* vb = Vt + (((size_t)bh * DH) << 10);
  const f16* kg = kb + (size_t)srow * 64 + scole;      // K: [T][64]
  const f16* vg = vb + (size_t)srow * TSEQ + scole;    // V^T: [64][T]

  const f16* qbase = Qg + (((size_t)bh * TSEQ + m0) << 6);
  f16x8 qf0 = *(const f16x8*)(qbase + am * 64 + ak);
  f16x8 qf1 = *(const f16x8*)(qbase + am * 64 + 32 + ak);
#pragma unroll
  for (int i = 0; i < 8; i++) { qf0[i] *= (f16)0.125f; qf1[i] *= (f16)0.125f; }

  f16* Pw = Plds[wv];
  f32x4 Oa[4];
#pragma unroll
  for (int i = 0; i < 4; i++) Oa[i] = (f32x4){0.f, 0.f, 0.f, 0.f};
  float lpart[4] = {0.f, 0.f, 0.f, 0.f};

  for (int n0 = 0; n0 < TSEQ; n0 += 64) {
    __syncthreads();  // previous tile fully consumed
#pragma unroll
    for (int j = 0; j < 2; j++) {
      glds16(kg + (size_t)(n0 + j * 8) * 64, &Ks[(wv * 16 + j * 8) * 64]);
      glds16(vg + (size_t)(j * 8) * TSEQ + n0, &Vs[(wv * 16 + j * 8) * 64]);
    }
    __syncthreads();  // vmcnt(0) drain: K/V tile landed

    int ce0 = 8 * (quad ^ sx);        // logical slot quad
    int ce1 = 8 * ((quad + 4) ^ sx);  // logical slot quad+4
    f32x4 S[4];
#pragma unroll
    for (int t = 0; t < 4; t++) {
      f16x8 kf0 = *(const f16x8*)&Ks[(16 * t + am) * 64 + ce0];
      f16x8 kf1 = *(const f16x8*)&Ks[(16 * t + am) * 64 + ce1];
      S[t] = __builtin_amdgcn_mfma_f32_16x16x32_f16(
          qf0, kf0, (f32x4){0.f, 0.f, 0.f, 0.f}, 0, 0, 0);
      S[t] = __builtin_amdgcn_mfma_f32_16x16x32_f16(qf1, kf1, S[t], 0, 0, 0);
    }
#pragma unroll
    for (int t = 0; t < 4; t++) {
#pragma unroll
      for (int r = 0; r < 4; r++) {
        float p = __expf(S[t][r]);
        lpart[r] += p;
        Pw[(quad * 4 + r) * PSTRIDE + 16 * t + am] = (f16)p;
      }
    }
    f16x8 pa0 = *(const f16x8*)&Pw[am * PSTRIDE + ak];
    f16x8 pa1 = *(const f16x8*)&Pw[am * PSTRIDE + 32 + ak];
#pragma unroll
    for (int dt = 0; dt < 4; dt++) {
      f16x8 vf0 = *(const f16x8*)&Vs[(16 * dt + am) * 64 + ce0];
      f16x8 vf1 = *(const f16x8*)&Vs[(16 * dt + am) * 64 + ce1];
      Oa[dt] = __builtin_amdgcn_mfma_f32_16x16x32_f16(pa0, vf0, Oa[dt], 0, 0, 0);
      Oa[dt] = __builtin_amdgcn_mfma_f32_16x16x32_f16(pa1, vf1, Oa[dt], 0, 0, 0);
    }
  }

#pragma unroll
  for (int o = 1; o < 16; o <<= 1)
#pragma unroll
    for (int r = 0; r < 4; r++) lpart[r] += __shfl_xor(lpart[r], o, 64);

#pragma unroll
  for (int r = 0; r < 4; r++) {
    int m = m0 + quad * 4 + r;
    float inv = 1.f / lpart[r];
    f16* orow = attn + ((size_t)(bb * TSEQ + m)) * CDIM + h * DH;
#pragma unroll
    for (int dt = 0; dt < 4; dt++)
      orow[dt * 16 + am] = (f16)(Oa[dt][r] * inv);
  }
}

// ---------------- Anderson update fused with next iteration's LN1 --------
template <int KA>
__global__ __launch_bounds__(256) void anderson_ln1(
    float* __restrict__ z, const float* __restrict__ rescur,
    const float* __restrict__ p0, const float* __restrict__ p1,
    const float* __restrict__ p2, const float* __restrict__ p3,
    const float* __restrict__ u, const float* __restrict__ emb,
    const float* __restrict__ w, const float* __restrict__ b,
    f16* __restrict__ x) {
  __shared__ float sbuf[4];
  int row = blockIdx.x, tid = threadIdx.x;
  size_t base = (size_t)row * CDIM + tid;
  float r[3];
#pragma unroll
  for (int i = 0; i < 3; i++) r[i] = rescur[base + i * 256];

  float zn[3];
  if constexpr (KA == 0) {
#pragma unroll
    for (int i = 0; i < 3; i++) zn[i] = z[base + i * 256] + r[i];
  } else {
    const float* ps[4] = {p0, p1, p2, p3};
    float dF[KA == 0 ? 1 : KA][3];
#pragma unroll
    for (int k = 0; k < KA; k++)
#pragma unroll
      for (int i = 0; i < 3; i++) dF[k][i] = ps[k][base + i * 256] - r[i];

    float Gm[KA == 0 ? 1 : KA][KA == 0 ? 1 : KA], bv[KA == 0 ? 1 : KA];
#pragma unroll
    for (int k = 0; k < KA; k++) {
#pragma unroll
      for (int ll = k; ll < KA; ll++) {
        float p = 0.f;
#pragma unroll
        for (int i = 0; i < 3; i++) p += dF[k][i] * dF[ll][i];
        float t = block_reduce_sum(p, sbuf);
        Gm[k][ll] = t;
        Gm[ll][k] = t;
      }
    }
#pragma unroll
    for (int k = 0; k < KA; k++) Gm[k][k] += 1e-6f;
#pragma unroll
    for (int k = 0; k < KA; k++) {
      float p = 0.f;
#pragma unroll
      for (int i = 0; i < 3; i++) p += dF[k][i] * r[i];
      bv[k] = block_reduce_sum(p, sbuf);
    }
    float alpha[KA == 0 ? 1 : KA];
#pragma unroll
    for (int p = 0; p < KA; p++) {
      float inv = 1.f / Gm[p][p];
#pragma unroll
      for (int rr = p + 1; rr < KA; rr++) {
        float f = Gm[rr][p] * inv;
#pragma unroll
        for (int c = p; c < KA; c++) Gm[rr][c] -= f * Gm[p][c];
        bv[rr] -= f * bv[p];
      }
    }
#pragma unroll
    for (int p = KA - 1; p >= 0; p--) {
      float s2 = bv[p];
#pragma unroll
      for (int c = p + 1; c < KA; c++) s2 -= Gm[p][c] * alpha[c];
      alpha[p] = s2 / Gm[p][p];
    }
#pragma unroll
    for (int i = 0; i < 3; i++) {
      float d = r[i];
#pragma unroll
      for (int k = 0; k < KA; k++) d = fmaf(-dF[k][i], alpha[k], d);
      zn[i] = z[base + i * 256] + d;
    }
  }
#pragma unroll
  for (int i = 0; i < 3; i++) z[base + i * 256] = zn[i];

  // ---- fused LN1 for next iteration ----
  const float* ur = u + (size_t)row * CDIM;
  float v[3];
  float s = 0.f;
#pragma unroll
  for (int i = 0; i < 3; i++) {
    int c = tid + i * 256;
    v[i] = zn[i] + 0.1f * emb[c] + ur[c];
    s += v[i];
  }
  s = block_reduce_sum(s, sbuf);
  float mu = s * (1.f / CDIM);
  float sq = 0.f;
#pragma unroll
  for (int i = 0; i < 3; i++) { v[i] -= mu; sq += v[i] * v[i]; }
  sq = block_reduce_sum(sq, sbuf);
  float rstd = rsqrtf(sq * (1.f / CDIM) + 1e-5f);
  f16* xr = x + (size_t)row * CDIM;
#pragma unroll
  for (int i = 0; i < 3; i++) {
    int c = tid + i * 256;
    xr[c] = (f16)(v[i] * rstd * w[c] + b[c]);
  }
}

// ---------------- Anderson (final iteration, no LN) -----------------------
template <int KA>
__global__ __launch_bounds__(256) void anderson_kernel(
    float* __restrict__ z, const float* __restrict__ rescur,
    const float* __restrict__ p0, const float* __restrict__ p1,
    const float* __restrict__ p2, const float* __restrict__ p3) {
  __shared__ float sbuf[4];
  int row = blockIdx.x, tid = threadIdx.x;
  size_t base = (size_t)row * CDIM + tid;
  float r[3];
#pragma unroll
  for (int i = 0; i < 3; i++) r[i] = rescur[base + i * 256];
  const float* ps[4] = {p0, p1, p2, p3};
  float dF[KA][3];
#pragma unroll
  for (int k = 0; k < KA; k++)
#pragma unroll
    for (int i = 0; i < 3; i++) dF[k][i] = ps[k][base + i * 256] - r[i];

  float Gm[KA][KA], bv[KA];
#pragma unroll
  for (int k = 0; k < KA; k++) {
#pragma unroll
    for (int ll = k; ll < KA; ll++) {
      float p = 0.f;
#pragma unroll
      for (int i = 0; i < 3; i++) p += dF[k][i] * dF[ll][i];
      float t = block_reduce_sum(p, sbuf);
      Gm[k][ll] = t;
      Gm[ll][k] = t;
    }
  }
#pragma unroll
  for (int k = 0; k < KA; k++) Gm[k][k] += 1e-6f;
#pragma unroll
  for (int k = 0; k < KA; k++) {
    float p = 0.f;
#pragma unroll
    for (int i = 0; i < 3; i++) p += dF[k][i] * r[i];
    bv[k] = block_reduce_sum(p, sbuf);
  }
  float alpha[KA];
#pragma unroll
  for (int p = 0; p < KA; p++) {
    float inv = 1.f / Gm[p][p];
#pragma unroll
    for (int rr = p + 1; rr < KA; rr++) {
      float f = Gm[rr][p] * inv;
#pragma unroll
      for (int c = p; c < KA; c++) Gm[rr][c] -= f * Gm[p][c];
      bv[rr] -= f * bv[p];
    }
  }
#pragma unroll
  for (int p = KA - 1; p >= 0; p--) {
    float s2 = bv[p];
#pragma unroll
    for (int c = p + 1; c < KA; c++) s2 -= Gm[p][c] * alpha[c];
    alpha[p] = s2 / Gm[p][p];
  }
#pragma unroll
  for (int i = 0; i < 3; i++) {
    float d = r[i];
#pragma unroll
    for (int k = 0; k < KA; k++) d = fmaf(-dF[k][i], alpha[k], d);
    z[base + i * 256] += d;
  }
}

extern "C" void kernel_launch(void* const* d_in, const int* in_sizes, int n_in,
                              void* d_out, int out_size, void* d_ws,
                              size_t ws_size, hipStream_t stream) {
  (void)in_sizes; (void)n_in; (void)out_size; (void)ws_size;
  const float* u = (const float*)d_in[0];
  const float* iter_emb = (const float*)d_in[1];
  const float* ln1w = (const float*)d_in[2];
  const float* ln1b = (const float*)d_in[3];
  const float* wqkv = (const float*)d_in[4];
  const float* bqkv = (const float*)d_in[5];
  const float* wo = (const float*)d_in[6];
  const float* bo = (const float*)d_in[7];
  const float* ln2w = (const float*)d_in[8];
  const float* ln2b = (const float*)d_in[9];
  const float* w1 = (const float*)d_in[10];
  const float* b1 = (const float*)d_in[11];
  const float* w2 = (const float*)d_in[12];
  const float* b2 = (const float*)d_in[13];

  const size_t S = (size_t)BT * CDIM;  // 3,145,728
  float* ws = (float*)d_ws;
  // fp32 slots:
  float* z = ws + 0 * S;
  float* zattn = ws + 1 * S;
  float* res[5] = {ws + 2 * S, ws + 3 * S, ws + 4 * S, ws + 5 * S, ws + 6 * S};
  // f16 region:
  f16* q_h = (f16*)(ws + 7 * S);   // S f16: [7.0,7.5)   [B,H,T,64]
  f16* k_h = q_h + S;              // [7.5,8.0)          [B,H,T,64]
  f16* vt_h = q_h + 2 * S;         // [8.0,8.5)          [B,H,64,T]
  f16* h_h = (f16*)(ws + 7 * S);   // 4S f16 [7.0,9.0) — aliases q/k/vt
                                   // (disjoint lifetime: mlp1..mlp2 only)
  f16* x_h = (f16*)(ws + 9 * S);   // S f16 [9.0,9.5): LN out / attn out
  f16* wqkv_h = x_h + S;
  f16* wo_h = wqkv_h + (size_t)3 * CDIM * CDIM;
  f16* w1_h = wo_h + (size_t)CDIM * CDIM;
  f16* w2_h = w1_h + (size_t)4 * CDIM * CDIM;

  cvt_f16_kernel<<<1728, 256, 0, stream>>>(wqkv, wqkv_h);
  cvt_f16_kernel<<<576, 256, 0, stream>>>(wo, wo_h);
  cvt_f16_kernel<<<2304, 256, 0, stream>>>(w1, w1_h);
  cvt_f16_kernel<<<2304, 256, 0, stream>>>(w2, w2_h);
  zero_kernel<<<S / 1024, 256, 0, stream>>>((float4*)z);

  for (int it = 0; it < 6; it++) {
    float* rcur = res[it % 5];
    if (it == 0) {
      ln1_kernel<<<BT, 256, 0, stream>>>(z, u, iter_emb, ln1w, ln1b, x_h);
    }
    // (it>0: x_h was produced by the fused anderson_ln1 of iteration it-1)
    gemm_mfma<3><<<dim3(18, 32), 256, 0, stream>>>(
        x_h, wqkv_h, bqkv, q_h, k_h, vt_h, nullptr, BT, 3 * CDIM, CDIM);
    flash_attn8<<<dim3(BBATCH * NHEAD, TSEQ / 64), 256, 0, stream>>>(
        q_h, k_h, vt_h, x_h);
    gemm_glds64<0><<<dim3(64, 12), 256, 0, stream>>>(
        x_h, wo_h, bo, z, zattn, BT, CDIM, CDIM);
    // ln2 also pre-initializes rcur = zattn - z + b2 for split-K atomics
    ln2_kernel<<<BT, 256, 0, stream>>>(zattn, ln2w, ln2b, x_h, z, b2, rcur);
    gemm_mfma<1><<<dim3(24, 32), 256, 0, stream>>>(
        x_h, w1_h, b1, nullptr, nullptr, nullptr, h_h, BT, 4 * CDIM, CDIM);
    gemm_glds64<4><<<dim3(64, 12, 2), 256, 0, stream>>>(
        h_h, w2_h, b2, nullptr, rcur, BT, CDIM, 4 * CDIM);

    int Kh = it < 4 ? it : 4;
    const float* p[4] = {rcur, rcur, rcur, rcur};
    for (int kx = 1; kx <= Kh; kx++) p[kx - 1] = res[(it - kx) % 5];
    if (it < 5) {
      const float* embn = iter_emb + (it + 1) * CDIM;
      switch (Kh) {
        case 0: anderson_ln1<0><<<BT, 256, 0, stream>>>(z, rcur, p[0], p[1], p[2], p[3], u, embn, ln1w, ln1b, x_h); break;
        case 1: anderson_ln1<1><<<BT, 256, 0, stream>>>(z, rcur, p[0], p[1], p[2], p[3], u, embn, ln1w, ln1b, x_h); break;
        case 2: anderson_ln1<2><<<BT, 256, 0, stream>>>(z, rcur, p[0], p[1], p[2], p[3], u, embn, ln1w, ln1b, x_h); break;
        case 3: anderson_ln1<3><<<BT, 256, 0, stream>>>(z, rcur, p[0], p[1], p[2], p[3], u, embn, ln1w, ln1b, x_h); break;
        default: anderson_ln1<4><<<BT, 256, 0, stream>>>(z, rcur, p[0], p[1], p[2], p[3], u, embn, ln1w, ln1b, x_h); break;
      }
    } else {
      anderson_kernel<4><<<BT, 256, 0, stream>>>(z, rcur, p[0], p[1], p[2], p[3]);
    }
  }
  hipMemcpyAsync(d_out, z, S * sizeof(float), hipMemcpyDeviceToDevice, stream);
}